// Round 1
// baseline (830.912 us; speedup 1.0000x reference)
//
#include <hip/hip_runtime.h>
#include <hip/hip_bf16.h>

// Problem constants (from reference)
#define NNODES 1000000
#define INDIM  128
#define HIDC   256
#define BSZ    4096
#define N2C    12288     // 3*B
#define FANC   10
#define N1C    122880    // N2*FAN
#define N0C    1228800   // N1*FAN

typedef __bf16 bf16_t;
typedef bf16_t bf16x2 __attribute__((ext_vector_type(2)));
typedef bf16_t bf16x4 __attribute__((ext_vector_type(4)));
typedef bf16_t bf16x8 __attribute__((ext_vector_type(8)));
typedef float  f32x4  __attribute__((ext_vector_type(4)));

// ---------------------------------------------------------------------------
// Weight prep: fp32 [K][N] (two stacked halves SA;SB) -> bf16 [N][Ktot] (row-major
// along K) so MFMA b-frags read 16B contiguous along K.
// ---------------------------------------------------------------------------
__global__ __launch_bounds__(256) void prep_w(const float* __restrict__ SA,
                                              const float* __restrict__ SB,
                                              bf16_t* __restrict__ dst,
                                              int Khalf, int Ktot, int N) {
  int t = blockIdx.x * 256 + threadIdx.x;
  if (t >= N * Ktot) return;
  int n = t / Ktot, k = t - n * Ktot;
  float v = (k < Khalf) ? SA[(size_t)k * N + n] : SB[(size_t)(k - Khalf) * N + n];
  dst[t] = (bf16_t)v;
}

// ---------------------------------------------------------------------------
// Layer-0 gather+aggregate. One wave per destination d < N1.
// A0 row d = [ node_feat[gids0[d]] (128) | mean_j node_feat[gids0[nidx0[d][j]]] (128) ] as bf16.
// Index chain kept in SGPRs (d is wave-uniform) -> s_loads; row reads are
// float2/lane = 512B coalesced per row.
// ---------------------------------------------------------------------------
__global__ __launch_bounds__(256) void gather0(const float* __restrict__ feat,
                                               const int* __restrict__ gids,
                                               const int* __restrict__ nidx,
                                               bf16_t* __restrict__ A0) {
  int wv = (blockIdx.x * 256 + threadIdx.x) >> 6;
  int d = __builtin_amdgcn_readfirstlane(wv);
  int lane = threadIdx.x & 63;
  const float2* f2 = (const float2*)feat;
  int idx[FANC];
#pragma unroll
  for (int j = 0; j < FANC; j++) idx[j] = nidx[d * FANC + j];
  int nid[FANC];
#pragma unroll
  for (int j = 0; j < FANC; j++) nid[j] = gids[idx[j]];
  float ax = 0.f, ay = 0.f;
#pragma unroll
  for (int j = 0; j < FANC; j++) {
    float2 v = f2[(size_t)nid[j] * 64 + lane];
    ax += v.x; ay += v.y;
  }
  int sn = gids[d];
  float2 xs = f2[(size_t)sn * 64 + lane];
  bf16_t* row = A0 + (size_t)d * 256;
  bf16x2 w0 = { (bf16_t)xs.x, (bf16_t)xs.y };
  *(bf16x2*)(row + lane * 2) = w0;
  bf16x2 w1 = { (bf16_t)(ax * 0.1f), (bf16_t)(ay * 0.1f) };
  *(bf16x2*)(row + 128 + lane * 2) = w1;
}

// ---------------------------------------------------------------------------
// Layer-1 gather+aggregate from bf16 h (L3-resident, 63MB).
// One wave per destination d < N2.  A1 row d = [ h[d] (256) | mean_j h[nidx1[d][j]] (256) ].
// ---------------------------------------------------------------------------
__global__ __launch_bounds__(256) void gather1(const bf16_t* __restrict__ h,
                                               const int* __restrict__ nidx,
                                               bf16_t* __restrict__ A1) {
  int wv = (blockIdx.x * 256 + threadIdx.x) >> 6;
  int d = __builtin_amdgcn_readfirstlane(wv);
  int lane = threadIdx.x & 63;
  const bf16x4* h4 = (const bf16x4*)h;
  int idx[FANC];
#pragma unroll
  for (int j = 0; j < FANC; j++) idx[j] = nidx[d * FANC + j];
  float a0 = 0.f, a1 = 0.f, a2 = 0.f, a3 = 0.f;
#pragma unroll
  for (int j = 0; j < FANC; j++) {
    bf16x4 v = h4[(size_t)idx[j] * 64 + lane];
    a0 += (float)v[0]; a1 += (float)v[1]; a2 += (float)v[2]; a3 += (float)v[3];
  }
  bf16x4 xs = h4[(size_t)d * 64 + lane];
  bf16x4* out = (bf16x4*)(A1 + (size_t)d * 512);
  out[lane] = xs;
  bf16x4 ag = { (bf16_t)(a0 * 0.1f), (bf16_t)(a1 * 0.1f),
                (bf16_t)(a2 * 0.1f), (bf16_t)(a3 * 0.1f) };
  out[64 + lane] = ag;
}

// ---------------------------------------------------------------------------
// bf16 MFMA GEMM, LDS-free: C(Mx256) = act(A(MxK) @ W(Kx256) + bias)
//   A: bf16 row-major (stride K); Wt: bf16 [N][K] (pre-transposed weights).
// Block = 256 thr = 4 waves; wave w owns cols [64w,64w+64); block owns MT*16 rows.
// A-frags stream from global (L1 catches the 4x reuse across waves);
// Wt (<=256KB) stays L2-resident across all blocks.
// mfma_f32_16x16x32_bf16 layouts (m89/m91-verified):
//   a-frag: A[m=lane&15][k=quad*8+j] ; b-frag: B[k=quad*8+j][n=lane&15]
//   d: row=quad*4+r, col=lane&15
// ---------------------------------------------------------------------------
template<int K, int MT, bool RELU, bool OUTBF>
__global__ __launch_bounds__(256) void gemm_mfma(const bf16_t* __restrict__ A,
                                                 const bf16_t* __restrict__ Wt,
                                                 const float* __restrict__ bias,
                                                 void* __restrict__ Cout) {
  int tid = threadIdx.x;
  int wv = tid >> 6, lane = tid & 63;
  int l15 = lane & 15, quad = lane >> 4;
  int m0 = blockIdx.x * (MT * 16);
  int n0 = wv * 64;
  f32x4 acc[MT][4] = {};
  for (int k0 = 0; k0 < K; k0 += 32) {
    bf16x8 a[MT], b[4];
#pragma unroll
    for (int mt = 0; mt < MT; mt++)
      a[mt] = *(const bf16x8*)(A + (size_t)(m0 + mt * 16 + l15) * K + k0 + quad * 8);
#pragma unroll
    for (int nt = 0; nt < 4; nt++)
      b[nt] = *(const bf16x8*)(Wt + (size_t)(n0 + nt * 16 + l15) * K + k0 + quad * 8);
#pragma unroll
    for (int mt = 0; mt < MT; mt++)
#pragma unroll
      for (int nt = 0; nt < 4; nt++)
        acc[mt][nt] = __builtin_amdgcn_mfma_f32_16x16x32_bf16(a[mt], b[nt], acc[mt][nt], 0, 0, 0);
  }
#pragma unroll
  for (int mt = 0; mt < MT; mt++) {
#pragma unroll
    for (int nt = 0; nt < 4; nt++) {
      int col = n0 + nt * 16 + l15;
      float bv = bias[col];
#pragma unroll
      for (int r = 0; r < 4; r++) {
        int row = m0 + mt * 16 + quad * 4 + r;
        float v = acc[mt][nt][r] + bv;
        if (RELU) v = fmaxf(v, 0.f);
        if (OUTBF) ((bf16_t*)Cout)[(size_t)row * 256 + col] = (bf16_t)v;
        else       ((float*)Cout)[(size_t)row * 256 + col] = v;
      }
    }
  }
}

// ---------------------------------------------------------------------------
// z = concat(src,src) * concat(pos,neg), bf16 out.  h2 is fp32 12288x256.
// z row r: a = r&4095, b = r+4096  (r<4096 -> pos rows, r>=4096 -> neg rows)
// ---------------------------------------------------------------------------
__global__ __launch_bounds__(256) void zbuild(const float* __restrict__ h2,
                                              bf16_t* __restrict__ z) {
  int t = blockIdx.x * 256 + threadIdx.x;   // 8192*64 threads, 4 cols each
  int r = t >> 6, c = (t & 63) * 4;
  int a = r & 4095, b = r + 4096;
  float4 va = *(const float4*)(h2 + (size_t)a * 256 + c);
  float4 vb = *(const float4*)(h2 + (size_t)b * 256 + c);
  bf16x4 o = { (bf16_t)(va.x * vb.x), (bf16_t)(va.y * vb.y),
               (bf16_t)(va.z * vb.z), (bf16_t)(va.w * vb.w) };
  *(bf16x4*)(z + (size_t)r * 256 + c) = o;
}

// ---------------------------------------------------------------------------
// Final: scores[i] = z2[i,:] . Wp3 + bp3   (fp32 accumulate, wave per row)
// ---------------------------------------------------------------------------
__global__ __launch_bounds__(256) void pred3(const bf16_t* __restrict__ z2,
                                             const float* __restrict__ Wp3,
                                             const float* __restrict__ bp3,
                                             float* __restrict__ out) {
  int wv = (blockIdx.x * 256 + threadIdx.x) >> 6;
  int lane = threadIdx.x & 63;
  bf16x4 v = ((const bf16x4*)z2)[(size_t)wv * 64 + lane];
  float4 w = ((const float4*)Wp3)[lane];
  float s = (float)v[0] * w.x + (float)v[1] * w.y + (float)v[2] * w.z + (float)v[3] * w.w;
  for (int off = 32; off > 0; off >>= 1) s += __shfl_down(s, off);
  if (lane == 0) out[wv] = s + bp3[0];
}

// ---------------------------------------------------------------------------
extern "C" void kernel_launch(void* const* d_in, const int* in_sizes, int n_in,
                              void* d_out, int out_size, void* d_ws, size_t ws_size,
                              hipStream_t stream) {
  const float* node_feat = (const float*)d_in[0];
  const int*   gids0     = (const int*)d_in[1];
  const int*   nidx0     = (const int*)d_in[2];
  const int*   nidx1     = (const int*)d_in[3];
  const float* Wself0    = (const float*)d_in[4];
  const float* Wneigh0   = (const float*)d_in[5];
  const float* b0        = (const float*)d_in[6];
  const float* Wself1    = (const float*)d_in[7];
  const float* Wneigh1   = (const float*)d_in[8];
  const float* b1        = (const float*)d_in[9];
  const float* Wp1       = (const float*)d_in[10];
  const float* bp1       = (const float*)d_in[11];
  const float* Wp2       = (const float*)d_in[12];
  const float* bp2       = (const float*)d_in[13];
  const float* Wp3       = (const float*)d_in[14];
  const float* bp3       = (const float*)d_in[15];

  // Workspace layout (total ~128 MB). A0 region is reused after gemm0:
  //   [A1 @ +0 | h2 @ +16MB | z @ +32MB | z1 @ +40MB | z2 @ +48MB] all < 63MB.
  char* ws = (char*)d_ws;
  bf16_t* Wt0  = (bf16_t*)(ws + 0);          // 256x256 bf16 = 128KB
  bf16_t* Wt1  = (bf16_t*)(ws + (128 << 10)); // 256x512 bf16 = 256KB
  bf16_t* WtP1 = (bf16_t*)(ws + (384 << 10)); // 128KB
  bf16_t* WtP2 = (bf16_t*)(ws + (512 << 10)); // 128KB
  char* big = ws + (1 << 20);
  bf16_t* A0 = (bf16_t*)big;                       // 122880x256 bf16 = 60MB
  bf16_t* h  = (bf16_t*)(big + 62914560ULL);       // 122880x256 bf16 = 60MB
  bf16_t* A1 = (bf16_t*)big;                       // 12288x512 bf16 (A0 dead)
  float*  h2 = (float*)(big + (16ULL << 20));      // 12288x256 f32
  bf16_t* z  = (bf16_t*)(big + (32ULL << 20));     // 8192x256 bf16
  bf16_t* z1 = (bf16_t*)(big + (40ULL << 20));
  bf16_t* z2 = (bf16_t*)(big + (48ULL << 20));
  float* out = (float*)d_out;

  // Weights -> bf16 [N][K] transposed layouts
  prep_w<<<256, 256, 0, stream>>>(Wself0, Wneigh0, Wt0, INDIM, 256, HIDC);
  prep_w<<<512, 256, 0, stream>>>(Wself1, Wneigh1, Wt1, HIDC, 512, HIDC);
  prep_w<<<256, 256, 0, stream>>>(Wp1, Wp1, WtP1, HIDC, 256, HIDC);
  prep_w<<<256, 256, 0, stream>>>(Wp2, Wp2, WtP2, HIDC, 256, HIDC);

  // Layer 0: gather/aggregate -> A0, then h = relu(A0 @ [Ws0;Wn0] + b0)
  gather0<<<N1C / 4, 256, 0, stream>>>(node_feat, gids0, nidx0, A0);
  gemm_mfma<256, 4, true, true><<<N1C / 64, 256, 0, stream>>>(A0, Wt0, b0, h);

  // Layer 1: gather/aggregate -> A1, then h2 = A1 @ [Ws1;Wn1] + b1 (no relu, fp32 out)
  gather1<<<N2C / 4, 256, 0, stream>>>(h, nidx1, A1);
  gemm_mfma<512, 2, false, false><<<N2C / 32, 256, 0, stream>>>(A1, Wt1, b1, h2);

  // Predictor
  zbuild<<<2048, 256, 0, stream>>>(h2, z);
  gemm_mfma<256, 2, true, true><<<8192 / 32, 256, 0, stream>>>(z,  WtP1, bp1, z1);
  gemm_mfma<256, 2, true, true><<<8192 / 32, 256, 0, stream>>>(z1, WtP2, bp2, z2);
  pred3<<<2048, 256, 0, stream>>>(z2, Wp3, bp3, out);
}

// Round 2
// 781.742 us; speedup vs baseline: 1.0629x; 1.0629x over previous
//
#include <hip/hip_runtime.h>
#include <hip/hip_bf16.h>

// Problem constants (from reference)
#define NNODES 1000000
#define INDIM  128
#define HIDC   256
#define BSZ    4096
#define N2C    12288     // 3*B
#define FANC   10
#define N1C    122880    // N2*FAN
#define N0C    1228800   // N1*FAN

typedef __bf16 bf16_t;
typedef bf16_t bf16x2 __attribute__((ext_vector_type(2)));
typedef bf16_t bf16x4 __attribute__((ext_vector_type(4)));
typedef bf16_t bf16x8 __attribute__((ext_vector_type(8)));
typedef float  f32x4  __attribute__((ext_vector_type(4)));

// ---------------------------------------------------------------------------
// Weight prep: fp32 [K][N] (two stacked halves SA;SB) -> bf16 [N][Ktot]
// (row-major along K) so MFMA b-frags read 16B contiguous along K.
// ---------------------------------------------------------------------------
__global__ __launch_bounds__(256) void prep_w(const float* __restrict__ SA,
                                              const float* __restrict__ SB,
                                              bf16_t* __restrict__ dst,
                                              int Khalf, int Ktot, int N) {
  int t = blockIdx.x * 256 + threadIdx.x;
  if (t >= N * Ktot) return;
  int n = t / Ktot, k = t - n * Ktot;
  float v = (k < Khalf) ? SA[(size_t)k * N + n] : SB[(size_t)(k - Khalf) * N + n];
  dst[t] = (bf16_t)v;
}

// ---------------------------------------------------------------------------
// FUSED layer-0: gather+mean-aggregate 64 dest rows into a padded LDS tile,
// then h[m0..m0+64) = relu(As @ [Ws0;Wn0] + b0) via MFMA reading A from LDS.
//   As row d = [ feat[gids[d]] (128) | mean_j feat[gids[nidx[d][j]]] (128) ] bf16
// LDS stride 264 bf16 (=528B, ≡ 4 banks mod 32 per row) -> ds_read_b128 sees
// only 2-way bank aliasing (free, m136).
// ---------------------------------------------------------------------------
#define LDA0 264
__global__ __launch_bounds__(256) void fused0(const float* __restrict__ feat,
                                              const int* __restrict__ gids,
                                              const int* __restrict__ nidx,
                                              const bf16_t* __restrict__ Wt,
                                              const float* __restrict__ bias,
                                              bf16_t* __restrict__ h) {
  __shared__ __align__(16) bf16_t As[64 * LDA0];   // 33792 B
  __shared__ int nid_s[64 * FANC];
  __shared__ int self_s[64];
  int tid = threadIdx.x;
  int m0 = blockIdx.x * 64;

  // phase 0: stage node ids (coalesced nidx read, random 4B gids gather)
  for (int t = tid; t < 64 * FANC; t += 256)
    nid_s[t] = gids[nidx[(size_t)m0 * FANC + t]];
  if (tid < 64) self_s[tid] = gids[m0 + tid];
  __syncthreads();

  // phase 1: row gathers. wave w handles dests [w*16, w*16+16); float2/lane.
  int wv = tid >> 6, lane = tid & 63;
  const float2* f2 = (const float2*)feat;
  for (int i = 0; i < 16; i++) {
    int d = wv * 16 + i;
    float ax = 0.f, ay = 0.f;
#pragma unroll
    for (int j = 0; j < FANC; j++) {
      int nd = nid_s[d * FANC + j];
      float2 v = f2[(size_t)nd * 64 + lane];
      ax += v.x; ay += v.y;
    }
    int sn = self_s[d];
    float2 xs = f2[(size_t)sn * 64 + lane];
    bf16_t* row = As + d * LDA0;
    bf16x2 w0 = { (bf16_t)xs.x, (bf16_t)xs.y };
    *(bf16x2*)(row + lane * 2) = w0;
    bf16x2 w1 = { (bf16_t)(ax * 0.1f), (bf16_t)(ay * 0.1f) };
    *(bf16x2*)(row + 128 + lane * 2) = w1;
  }
  __syncthreads();

  // phase 2: MFMA. wave w owns cols [64w, 64w+64); 4 m-tiles of 16 rows.
  int l15 = lane & 15, quad = lane >> 4;
  int n0 = wv * 64;
  f32x4 acc[4][4] = {};
  for (int k0 = 0; k0 < 256; k0 += 32) {
    bf16x8 a[4], b[4];
#pragma unroll
    for (int mt = 0; mt < 4; mt++)
      a[mt] = *(const bf16x8*)(As + (mt * 16 + l15) * LDA0 + k0 + quad * 8);
#pragma unroll
    for (int nt = 0; nt < 4; nt++)
      b[nt] = *(const bf16x8*)(Wt + (size_t)(n0 + nt * 16 + l15) * 256 + k0 + quad * 8);
#pragma unroll
    for (int mt = 0; mt < 4; mt++)
#pragma unroll
      for (int nt = 0; nt < 4; nt++)
        acc[mt][nt] = __builtin_amdgcn_mfma_f32_16x16x32_bf16(a[mt], b[nt], acc[mt][nt], 0, 0, 0);
  }
#pragma unroll
  for (int mt = 0; mt < 4; mt++)
#pragma unroll
    for (int nt = 0; nt < 4; nt++) {
      int col = n0 + nt * 16 + l15;
      float bv = bias[col];
#pragma unroll
      for (int r = 0; r < 4; r++) {
        int row = m0 + mt * 16 + quad * 4 + r;
        float v = fmaxf(acc[mt][nt][r] + bv, 0.f);
        h[(size_t)row * 256 + col] = (bf16_t)v;
      }
    }
}

// ---------------------------------------------------------------------------
// FUSED layer-1: gather+aggregate 32 dest rows from bf16 h (L3-resident) into
// LDS, then h2[m0..m0+32) = As1 @ [Ws1;Wn1] + b1 (fp32 out, no relu). K=512.
// ---------------------------------------------------------------------------
#define LDA1 520
__global__ __launch_bounds__(256) void fused1(const bf16_t* __restrict__ h,
                                              const int* __restrict__ nidx,
                                              const bf16_t* __restrict__ Wt,
                                              const float* __restrict__ bias,
                                              float* __restrict__ h2) {
  __shared__ __align__(16) bf16_t As[32 * LDA1];   // 33280 B
  __shared__ int nid_s[32 * FANC];
  int tid = threadIdx.x;
  int m0 = blockIdx.x * 32;

  for (int t = tid; t < 32 * FANC; t += 256)
    nid_s[t] = nidx[(size_t)m0 * FANC + t];
  __syncthreads();

  int wv = tid >> 6, lane = tid & 63;
  const bf16x4* h4 = (const bf16x4*)h;
  for (int i = 0; i < 8; i++) {
    int d = wv * 8 + i;
    float a0 = 0.f, a1 = 0.f, a2 = 0.f, a3 = 0.f;
#pragma unroll
    for (int j = 0; j < FANC; j++) {
      int nd = nid_s[d * FANC + j];
      bf16x4 v = h4[(size_t)nd * 64 + lane];
      a0 += (float)v[0]; a1 += (float)v[1]; a2 += (float)v[2]; a3 += (float)v[3];
    }
    bf16x4 xs = h4[(size_t)(m0 + d) * 64 + lane];
    bf16_t* row = As + d * LDA1;
    *(bf16x4*)(row + lane * 4) = xs;
    bf16x4 ag = { (bf16_t)(a0 * 0.1f), (bf16_t)(a1 * 0.1f),
                  (bf16_t)(a2 * 0.1f), (bf16_t)(a3 * 0.1f) };
    *(bf16x4*)(row + 256 + lane * 4) = ag;
  }
  __syncthreads();

  int l15 = lane & 15, quad = lane >> 4;
  int n0 = wv * 64;
  f32x4 acc[2][4] = {};
  for (int k0 = 0; k0 < 512; k0 += 32) {
    bf16x8 a[2], b[4];
#pragma unroll
    for (int mt = 0; mt < 2; mt++)
      a[mt] = *(const bf16x8*)(As + (mt * 16 + l15) * LDA1 + k0 + quad * 8);
#pragma unroll
    for (int nt = 0; nt < 4; nt++)
      b[nt] = *(const bf16x8*)(Wt + (size_t)(n0 + nt * 16 + l15) * 512 + k0 + quad * 8);
#pragma unroll
    for (int mt = 0; mt < 2; mt++)
#pragma unroll
      for (int nt = 0; nt < 4; nt++)
        acc[mt][nt] = __builtin_amdgcn_mfma_f32_16x16x32_bf16(a[mt], b[nt], acc[mt][nt], 0, 0, 0);
  }
#pragma unroll
  for (int mt = 0; mt < 2; mt++)
#pragma unroll
    for (int nt = 0; nt < 4; nt++) {
      int col = n0 + nt * 16 + l15;
      float bv = bias[col];
#pragma unroll
      for (int r = 0; r < 4; r++) {
        int row = m0 + mt * 16 + quad * 4 + r;
        h2[(size_t)row * 256 + col] = acc[mt][nt][r] + bv;
      }
    }
}

// ---------------------------------------------------------------------------
// bf16 MFMA GEMM, LDS-free (predictor layers): C = act(A @ W + b)
// ---------------------------------------------------------------------------
template<int K, int MT, bool RELU, bool OUTBF>
__global__ __launch_bounds__(256) void gemm_mfma(const bf16_t* __restrict__ A,
                                                 const bf16_t* __restrict__ Wt,
                                                 const float* __restrict__ bias,
                                                 void* __restrict__ Cout) {
  int tid = threadIdx.x;
  int wv = tid >> 6, lane = tid & 63;
  int l15 = lane & 15, quad = lane >> 4;
  int m0 = blockIdx.x * (MT * 16);
  int n0 = wv * 64;
  f32x4 acc[MT][4] = {};
  for (int k0 = 0; k0 < K; k0 += 32) {
    bf16x8 a[MT], b[4];
#pragma unroll
    for (int mt = 0; mt < MT; mt++)
      a[mt] = *(const bf16x8*)(A + (size_t)(m0 + mt * 16 + l15) * K + k0 + quad * 8);
#pragma unroll
    for (int nt = 0; nt < 4; nt++)
      b[nt] = *(const bf16x8*)(Wt + (size_t)(n0 + nt * 16 + l15) * K + k0 + quad * 8);
#pragma unroll
    for (int mt = 0; mt < MT; mt++)
#pragma unroll
      for (int nt = 0; nt < 4; nt++)
        acc[mt][nt] = __builtin_amdgcn_mfma_f32_16x16x32_bf16(a[mt], b[nt], acc[mt][nt], 0, 0, 0);
  }
#pragma unroll
  for (int mt = 0; mt < MT; mt++)
#pragma unroll
    for (int nt = 0; nt < 4; nt++) {
      int col = n0 + nt * 16 + l15;
      float bv = bias[col];
#pragma unroll
      for (int r = 0; r < 4; r++) {
        int row = m0 + mt * 16 + quad * 4 + r;
        float v = acc[mt][nt][r] + bv;
        if (RELU) v = fmaxf(v, 0.f);
        if (OUTBF) ((bf16_t*)Cout)[(size_t)row * 256 + col] = (bf16_t)v;
        else       ((float*)Cout)[(size_t)row * 256 + col] = v;
      }
    }
}

// ---------------------------------------------------------------------------
// z = concat(src,src) * concat(pos,neg), bf16 out.  h2 is fp32 12288x256.
// ---------------------------------------------------------------------------
__global__ __launch_bounds__(256) void zbuild(const float* __restrict__ h2,
                                              bf16_t* __restrict__ z) {
  int t = blockIdx.x * 256 + threadIdx.x;
  int r = t >> 6, c = (t & 63) * 4;
  int a = r & 4095, b = r + 4096;
  float4 va = *(const float4*)(h2 + (size_t)a * 256 + c);
  float4 vb = *(const float4*)(h2 + (size_t)b * 256 + c);
  bf16x4 o = { (bf16_t)(va.x * vb.x), (bf16_t)(va.y * vb.y),
               (bf16_t)(va.z * vb.z), (bf16_t)(va.w * vb.w) };
  *(bf16x4*)(z + (size_t)r * 256 + c) = o;
}

// ---------------------------------------------------------------------------
// Final: scores[i] = z2[i,:] . Wp3 + bp3   (fp32 accumulate, wave per row)
// ---------------------------------------------------------------------------
__global__ __launch_bounds__(256) void pred3(const bf16_t* __restrict__ z2,
                                             const float* __restrict__ Wp3,
                                             const float* __restrict__ bp3,
                                             float* __restrict__ out) {
  int wv = (blockIdx.x * 256 + threadIdx.x) >> 6;
  int lane = threadIdx.x & 63;
  bf16x4 v = ((const bf16x4*)z2)[(size_t)wv * 64 + lane];
  float4 w = ((const float4*)Wp3)[lane];
  float s = (float)v[0] * w.x + (float)v[1] * w.y + (float)v[2] * w.z + (float)v[3] * w.w;
  for (int off = 32; off > 0; off >>= 1) s += __shfl_down(s, off);
  if (lane == 0) out[wv] = s + bp3[0];
}

// ---------------------------------------------------------------------------
extern "C" void kernel_launch(void* const* d_in, const int* in_sizes, int n_in,
                              void* d_out, int out_size, void* d_ws, size_t ws_size,
                              hipStream_t stream) {
  const float* node_feat = (const float*)d_in[0];
  const int*   gids0     = (const int*)d_in[1];
  const int*   nidx0     = (const int*)d_in[2];
  const int*   nidx1     = (const int*)d_in[3];
  const float* Wself0    = (const float*)d_in[4];
  const float* Wneigh0   = (const float*)d_in[5];
  const float* b0        = (const float*)d_in[6];
  const float* Wself1    = (const float*)d_in[7];
  const float* Wneigh1   = (const float*)d_in[8];
  const float* b1        = (const float*)d_in[9];
  const float* Wp1       = (const float*)d_in[10];
  const float* bp1       = (const float*)d_in[11];
  const float* Wp2       = (const float*)d_in[12];
  const float* bp2       = (const float*)d_in[13];
  const float* Wp3       = (const float*)d_in[14];
  const float* bp3       = (const float*)d_in[15];

  char* ws = (char*)d_ws;
  bf16_t* Wt0  = (bf16_t*)(ws + 0);           // 256x256 bf16 = 128KB
  bf16_t* Wt1  = (bf16_t*)(ws + (128 << 10)); // 256x512 bf16 = 256KB
  bf16_t* WtP1 = (bf16_t*)(ws + (384 << 10));
  bf16_t* WtP2 = (bf16_t*)(ws + (512 << 10));
  char* big = ws + (1 << 20);
  bf16_t* h  = (bf16_t*)big;                       // 122880x256 bf16 = 60MB
  float*  h2 = (float*)(big + (64ULL << 20));      // 12288x256 f32 = 12MB
  bf16_t* z  = (bf16_t*)(big + (80ULL << 20));     // 8192x256 bf16 = 4MB
  bf16_t* z1 = (bf16_t*)(big + (88ULL << 20));
  bf16_t* z2 = (bf16_t*)(big + (96ULL << 20));
  float* out = (float*)d_out;

  // Weights -> bf16 [N][K] transposed layouts
  prep_w<<<256, 256, 0, stream>>>(Wself0, Wneigh0, Wt0, INDIM, 256, HIDC);
  prep_w<<<512, 256, 0, stream>>>(Wself1, Wneigh1, Wt1, HIDC, 512, HIDC);
  prep_w<<<256, 256, 0, stream>>>(Wp1, Wp1, WtP1, HIDC, 256, HIDC);
  prep_w<<<256, 256, 0, stream>>>(Wp2, Wp2, WtP2, HIDC, 256, HIDC);

  // Layer 0 fused: h = relu([x|agg] @ [Ws0;Wn0] + b0)
  fused0<<<N1C / 64, 256, 0, stream>>>(node_feat, gids0, nidx0, Wt0, b0, h);

  // Layer 1 fused: h2 = [h|agg] @ [Ws1;Wn1] + b1
  fused1<<<N2C / 32, 256, 0, stream>>>(h, nidx1, Wt1, b1, h2);

  // Predictor
  zbuild<<<2048, 256, 0, stream>>>(h2, z);
  gemm_mfma<256, 2, true, true><<<8192 / 32, 256, 0, stream>>>(z,  WtP1, bp1, z1);
  gemm_mfma<256, 2, true, true><<<8192 / 32, 256, 0, stream>>>(z1, WtP2, bp2, z2);
  pred3<<<2048, 256, 0, stream>>>(z2, Wp3, bp3, out);
}

// Round 3
// 742.323 us; speedup vs baseline: 1.1193x; 1.0531x over previous
//
#include <hip/hip_runtime.h>
#include <hip/hip_bf16.h>

// Problem constants (from reference)
#define NNODES 1000000
#define INDIM  128
#define HIDC   256
#define BSZ    4096
#define N2C    12288     // 3*B
#define FANC   10
#define N1C    122880    // N2*FAN
#define N0C    1228800   // N1*FAN

typedef __bf16 bf16_t;
typedef bf16_t bf16x2 __attribute__((ext_vector_type(2)));
typedef bf16_t bf16x4 __attribute__((ext_vector_type(4)));
typedef bf16_t bf16x8 __attribute__((ext_vector_type(8)));
typedef float  f32x4  __attribute__((ext_vector_type(4)));

// ---------------------------------------------------------------------------
// All weight prep in ONE launch: fp32 [K][N] (optionally stacked SA;SB) ->
// bf16 [N][Ktot] so MFMA b-frags read 16B contiguous along K.
//   job0: Wt0  = [Ws0;Wn0]^T  (N=256, Ktot=256, Khalf=128)   t in [0, 65536)
//   job1: Wt1  = [Ws1;Wn1]^T  (N=256, Ktot=512, Khalf=256)   t in [65536, 196608)
//   job2: WtP1 = Wp1^T         (256x256)                      t in [196608, 262144)
//   job3: WtP2 = Wp2^T         (256x256)                      t in [262144, 327680)
// ---------------------------------------------------------------------------
__global__ __launch_bounds__(256) void prep_all(const float* __restrict__ Ws0,
                                                const float* __restrict__ Wn0,
                                                const float* __restrict__ Ws1,
                                                const float* __restrict__ Wn1,
                                                const float* __restrict__ Wp1,
                                                const float* __restrict__ Wp2,
                                                bf16_t* __restrict__ Wt0,
                                                bf16_t* __restrict__ Wt1,
                                                bf16_t* __restrict__ WtP1,
                                                bf16_t* __restrict__ WtP2) {
  int t = blockIdx.x * 256 + threadIdx.x;
  if (t < 65536) {
    int n = t >> 8, k = t & 255;
    float v = (k < 128) ? Ws0[k * 256 + n] : Wn0[(k - 128) * 256 + n];
    Wt0[t] = (bf16_t)v;
  } else if (t < 196608) {
    int u = t - 65536; int n = u >> 9, k = u & 511;
    float v = (k < 256) ? Ws1[k * 256 + n] : Wn1[(k - 256) * 256 + n];
    Wt1[u] = (bf16_t)v;
  } else if (t < 262144) {
    int u = t - 196608; int n = u >> 8, k = u & 255;
    WtP1[u] = (bf16_t)Wp1[k * 256 + n];
  } else {
    int u = t - 262144; int n = u >> 8, k = u & 255;
    WtP2[u] = (bf16_t)Wp2[k * 256 + n];
  }
}

// ---------------------------------------------------------------------------
// FUSED layer-0: gather+mean-aggregate 64 dest rows into a padded LDS tile,
// then h[m0..m0+64) = relu(As @ [Ws0;Wn0] + b0) via MFMA reading A from LDS.
//   As row d = [ feat[gids[d]] (128) | mean_j feat[gids[nidx[d][j]]] (128) ] bf16
// LDS stride 264 bf16 (528B): 16B-aligned rows, ds_read_b128 sees only 2-way
// bank aliasing (free per m136). This kernel is the random-gather HBM floor:
// 1.35M x 512B unique-ish fp32 row reads ~ 690 MB.
// ---------------------------------------------------------------------------
#define LDA0 264
__global__ __launch_bounds__(256) void fused0(const float* __restrict__ feat,
                                              const int* __restrict__ gids,
                                              const int* __restrict__ nidx,
                                              const bf16_t* __restrict__ Wt,
                                              const float* __restrict__ bias,
                                              bf16_t* __restrict__ h) {
  __shared__ __align__(16) bf16_t As[64 * LDA0];   // 33792 B
  __shared__ int nid_s[64 * FANC];
  __shared__ int self_s[64];
  int tid = threadIdx.x;
  int m0 = blockIdx.x * 64;

  // phase 0: stage node ids (coalesced nidx read, random 4B gids gather)
  for (int t = tid; t < 64 * FANC; t += 256)
    nid_s[t] = gids[nidx[(size_t)m0 * FANC + t]];
  if (tid < 64) self_s[tid] = gids[m0 + tid];
  __syncthreads();

  // phase 1: row gathers. wave w handles dests [w*16, w*16+16); float2/lane.
  int wv = tid >> 6, lane = tid & 63;
  const float2* f2 = (const float2*)feat;
  for (int i = 0; i < 16; i++) {
    int d = wv * 16 + i;
    float ax = 0.f, ay = 0.f;
#pragma unroll
    for (int j = 0; j < FANC; j++) {
      int nd = nid_s[d * FANC + j];
      float2 v = f2[(size_t)nd * 64 + lane];
      ax += v.x; ay += v.y;
    }
    int sn = self_s[d];
    float2 xs = f2[(size_t)sn * 64 + lane];
    bf16_t* row = As + d * LDA0;
    bf16x2 w0 = { (bf16_t)xs.x, (bf16_t)xs.y };
    *(bf16x2*)(row + lane * 2) = w0;
    bf16x2 w1 = { (bf16_t)(ax * 0.1f), (bf16_t)(ay * 0.1f) };
    *(bf16x2*)(row + 128 + lane * 2) = w1;
  }
  __syncthreads();

  // phase 2: MFMA. wave w owns cols [64w, 64w+64); 4 m-tiles of 16 rows.
  int l15 = lane & 15, quad = lane >> 4;
  int n0 = wv * 64;
  f32x4 acc[4][4] = {};
  for (int k0 = 0; k0 < 256; k0 += 32) {
    bf16x8 a[4], b[4];
#pragma unroll
    for (int mt = 0; mt < 4; mt++)
      a[mt] = *(const bf16x8*)(As + (mt * 16 + l15) * LDA0 + k0 + quad * 8);
#pragma unroll
    for (int nt = 0; nt < 4; nt++)
      b[nt] = *(const bf16x8*)(Wt + (size_t)(n0 + nt * 16 + l15) * 256 + k0 + quad * 8);
#pragma unroll
    for (int mt = 0; mt < 4; mt++)
#pragma unroll
      for (int nt = 0; nt < 4; nt++)
        acc[mt][nt] = __builtin_amdgcn_mfma_f32_16x16x32_bf16(a[mt], b[nt], acc[mt][nt], 0, 0, 0);
  }
#pragma unroll
  for (int mt = 0; mt < 4; mt++)
#pragma unroll
    for (int nt = 0; nt < 4; nt++) {
      int col = n0 + nt * 16 + l15;
      float bv = bias[col];
#pragma unroll
      for (int r = 0; r < 4; r++) {
        int row = m0 + mt * 16 + quad * 4 + r;
        float v = fmaxf(acc[mt][nt][r] + bv, 0.f);
        h[(size_t)row * 256 + col] = (bf16_t)v;
      }
    }
}

// ---------------------------------------------------------------------------
// FUSED layer-1: gather+aggregate 32 dest rows from bf16 h (L3-resident) into
// LDS, then h2[m0..m0+32) = As1 @ [Ws1;Wn1] + b1 (fp32 out, no relu). K=512.
// ---------------------------------------------------------------------------
#define LDA1 520
__global__ __launch_bounds__(256) void fused1(const bf16_t* __restrict__ h,
                                              const int* __restrict__ nidx,
                                              const bf16_t* __restrict__ Wt,
                                              const float* __restrict__ bias,
                                              float* __restrict__ h2) {
  __shared__ __align__(16) bf16_t As[32 * LDA1];   // 33280 B
  __shared__ int nid_s[32 * FANC];
  int tid = threadIdx.x;
  int m0 = blockIdx.x * 32;

  for (int t = tid; t < 32 * FANC; t += 256)
    nid_s[t] = nidx[(size_t)m0 * FANC + t];
  __syncthreads();

  int wv = tid >> 6, lane = tid & 63;
  const bf16x4* h4 = (const bf16x4*)h;
  for (int i = 0; i < 8; i++) {
    int d = wv * 8 + i;
    float a0 = 0.f, a1 = 0.f, a2 = 0.f, a3 = 0.f;
#pragma unroll
    for (int j = 0; j < FANC; j++) {
      int nd = nid_s[d * FANC + j];
      bf16x4 v = h4[(size_t)nd * 64 + lane];
      a0 += (float)v[0]; a1 += (float)v[1]; a2 += (float)v[2]; a3 += (float)v[3];
    }
    bf16x4 xs = h4[(size_t)(m0 + d) * 64 + lane];
    bf16_t* row = As + d * LDA1;
    *(bf16x4*)(row + lane * 4) = xs;
    bf16x4 ag = { (bf16_t)(a0 * 0.1f), (bf16_t)(a1 * 0.1f),
                  (bf16_t)(a2 * 0.1f), (bf16_t)(a3 * 0.1f) };
    *(bf16x4*)(row + 256 + lane * 4) = ag;
  }
  __syncthreads();

  int l15 = lane & 15, quad = lane >> 4;
  int n0 = wv * 64;
  f32x4 acc[2][4] = {};
  for (int k0 = 0; k0 < 512; k0 += 32) {
    bf16x8 a[2], b[4];
#pragma unroll
    for (int mt = 0; mt < 2; mt++)
      a[mt] = *(const bf16x8*)(As + (mt * 16 + l15) * LDA1 + k0 + quad * 8);
#pragma unroll
    for (int nt = 0; nt < 4; nt++)
      b[nt] = *(const bf16x8*)(Wt + (size_t)(n0 + nt * 16 + l15) * 512 + k0 + quad * 8);
#pragma unroll
    for (int mt = 0; mt < 2; mt++)
#pragma unroll
      for (int nt = 0; nt < 4; nt++)
        acc[mt][nt] = __builtin_amdgcn_mfma_f32_16x16x32_bf16(a[mt], b[nt], acc[mt][nt], 0, 0, 0);
  }
#pragma unroll
  for (int mt = 0; mt < 2; mt++)
#pragma unroll
    for (int nt = 0; nt < 4; nt++) {
      int col = n0 + nt * 16 + l15;
      float bv = bias[col];
#pragma unroll
      for (int r = 0; r < 4; r++) {
        int row = m0 + mt * 16 + quad * 4 + r;
        h2[(size_t)row * 256 + col] = acc[mt][nt][r] + bv;
      }
    }
}

// ---------------------------------------------------------------------------
// FUSED predictor: per block, 64 z-rows end-to-end.
//   z[r] = h2[r&4095] * h2[r+4096]  (bf16, LDS buf0)
//   z1   = relu(z @ Wp1 + bp1)       (bf16, LDS buf1)
//   z2   = relu(z1 @ Wp2 + bp2)      (bf16, LDS buf0, overwrites z after sync)
//   out[r] = z2[r,:] . Wp3 + bp3     (fp32 wave reduce)
// Weights stream from L2 (128KB each, reused by all 128 blocks).
// ---------------------------------------------------------------------------
#define LDP 264
__device__ __forceinline__ void gemm_tile_lds(const bf16_t* __restrict__ Asrc,
                                              const bf16_t* __restrict__ Wt,
                                              const float* __restrict__ bias,
                                              bf16_t* __restrict__ Dst,
                                              int wv, int lane) {
  int l15 = lane & 15, quad = lane >> 4;
  int n0 = wv * 64;
  f32x4 acc[4][4] = {};
  for (int k0 = 0; k0 < 256; k0 += 32) {
    bf16x8 a[4], b[4];
#pragma unroll
    for (int mt = 0; mt < 4; mt++)
      a[mt] = *(const bf16x8*)(Asrc + (mt * 16 + l15) * LDP + k0 + quad * 8);
#pragma unroll
    for (int nt = 0; nt < 4; nt++)
      b[nt] = *(const bf16x8*)(Wt + (size_t)(n0 + nt * 16 + l15) * 256 + k0 + quad * 8);
#pragma unroll
    for (int mt = 0; mt < 4; mt++)
#pragma unroll
      for (int nt = 0; nt < 4; nt++)
        acc[mt][nt] = __builtin_amdgcn_mfma_f32_16x16x32_bf16(a[mt], b[nt], acc[mt][nt], 0, 0, 0);
  }
#pragma unroll
  for (int mt = 0; mt < 4; mt++)
#pragma unroll
    for (int nt = 0; nt < 4; nt++) {
      int col = n0 + nt * 16 + l15;
      float bv = bias[col];
#pragma unroll
      for (int r = 0; r < 4; r++) {
        int row = mt * 16 + quad * 4 + r;
        Dst[row * LDP + col] = (bf16_t)fmaxf(acc[mt][nt][r] + bv, 0.f);
      }
    }
}

__global__ __launch_bounds__(256) void pred_fused(const float* __restrict__ h2,
                                                  const bf16_t* __restrict__ WtP1,
                                                  const float* __restrict__ bp1,
                                                  const bf16_t* __restrict__ WtP2,
                                                  const float* __restrict__ bp2,
                                                  const float* __restrict__ Wp3,
                                                  const float* __restrict__ bp3,
                                                  float* __restrict__ out) {
  __shared__ __align__(16) bf16_t Z0[64 * LDP];
  __shared__ __align__(16) bf16_t Z1[64 * LDP];
  int tid = threadIdx.x, wv = tid >> 6, lane = tid & 63;
  int m0 = blockIdx.x * 64;

  // phase A: build z tile (rows m0..m0+64)
  for (int i = 0; i < 16; i++) {
    int rl = wv * 16 + i;
    int r = m0 + rl;
    int a = r & 4095, b = r + 4096;
    float4 va = *(const float4*)(h2 + (size_t)a * 256 + lane * 4);
    float4 vb = *(const float4*)(h2 + (size_t)b * 256 + lane * 4);
    bf16x4 o = { (bf16_t)(va.x * vb.x), (bf16_t)(va.y * vb.y),
                 (bf16_t)(va.z * vb.z), (bf16_t)(va.w * vb.w) };
    *(bf16x4*)(Z0 + rl * LDP + lane * 4) = o;
  }
  __syncthreads();

  // phase B/C: two GEMMs, ping-pong
  gemm_tile_lds(Z0, WtP1, bp1, Z1, wv, lane);
  __syncthreads();
  gemm_tile_lds(Z1, WtP2, bp2, Z0, wv, lane);
  __syncthreads();

  // phase D: scores
  float4 w = *(const float4*)(Wp3 + lane * 4);
  float b3 = bp3[0];
  for (int i = 0; i < 16; i++) {
    int rl = wv * 16 + i;
    bf16x4 v = *(const bf16x4*)(Z0 + rl * LDP + lane * 4);
    float s = (float)v[0] * w.x + (float)v[1] * w.y + (float)v[2] * w.z + (float)v[3] * w.w;
    for (int off = 32; off > 0; off >>= 1) s += __shfl_down(s, off);
    if (lane == 0) out[m0 + rl] = s + b3;
  }
}

// ---------------------------------------------------------------------------
extern "C" void kernel_launch(void* const* d_in, const int* in_sizes, int n_in,
                              void* d_out, int out_size, void* d_ws, size_t ws_size,
                              hipStream_t stream) {
  const float* node_feat = (const float*)d_in[0];
  const int*   gids0     = (const int*)d_in[1];
  const int*   nidx0     = (const int*)d_in[2];
  const int*   nidx1     = (const int*)d_in[3];
  const float* Wself0    = (const float*)d_in[4];
  const float* Wneigh0   = (const float*)d_in[5];
  const float* b0        = (const float*)d_in[6];
  const float* Wself1    = (const float*)d_in[7];
  const float* Wneigh1   = (const float*)d_in[8];
  const float* b1        = (const float*)d_in[9];
  const float* Wp1       = (const float*)d_in[10];
  const float* bp1       = (const float*)d_in[11];
  const float* Wp2       = (const float*)d_in[12];
  const float* bp2       = (const float*)d_in[13];
  const float* Wp3       = (const float*)d_in[14];
  const float* bp3       = (const float*)d_in[15];

  char* ws = (char*)d_ws;
  bf16_t* Wt0  = (bf16_t*)(ws + 0);           // 256x256 bf16 = 128KB
  bf16_t* Wt1  = (bf16_t*)(ws + (128 << 10)); // 256x512 bf16 = 256KB
  bf16_t* WtP1 = (bf16_t*)(ws + (384 << 10));
  bf16_t* WtP2 = (bf16_t*)(ws + (512 << 10));
  char* big = ws + (1 << 20);
  bf16_t* h  = (bf16_t*)big;                       // 122880x256 bf16 = 60MB
  float*  h2 = (float*)(big + (64ULL << 20));      // 12288x256 f32 = 12MB
  float* out = (float*)d_out;

  // Single weight-prep launch
  prep_all<<<1280, 256, 0, stream>>>(Wself0, Wneigh0, Wself1, Wneigh1, Wp1, Wp2,
                                     Wt0, Wt1, WtP1, WtP2);

  // Layer 0 fused: h = relu([x|agg] @ [Ws0;Wn0] + b0)
  fused0<<<N1C / 64, 256, 0, stream>>>(node_feat, gids0, nidx0, Wt0, b0, h);

  // Layer 1 fused: h2 = [h|agg] @ [Ws1;Wn1] + b1
  fused1<<<N2C / 32, 256, 0, stream>>>(h, nidx1, Wt1, b1, h2);

  // Predictor fused: z -> P1 -> P2 -> P3 in one kernel
  pred_fused<<<8192 / 64, 256, 0, stream>>>(h2, WtP1, bp1, WtP2, bp2, Wp3, bp3, out);
}